// Round 12
// baseline (76.241 us; speedup 1.0000x reference)
//
#include <hip/hip_runtime.h>

#define BN_EPS 1e-5f

typedef short short8 __attribute__((ext_vector_type(8)));
typedef float f32x4 __attribute__((ext_vector_type(4)));
typedef unsigned short ushort;

__device__ inline ushort f2bf(float f) {
  unsigned int u = __float_as_uint(f);
  u += 0x7FFFu + ((u >> 16) & 1u);
  return (ushort)(u >> 16);
}

// ws float-word layout:
//   [0..5]           stats (3 sums, 3 sumsqs)
//   [64..39999]      psumA [6][6656]
//   [45056..85055]   probe dead region
//   [131072..262143] WgtB  bf16 (512 KB)
//   [262144..524287] featB bf16 [512][2048] (2 MB)
//   [786432..]       S     [9][346112] fp32 (12.5 MB)

#define NPOS 346112  // 512*676
#define LR 136       // per-wave LDS row stride (floats)
#define NW 6656      // 512*13 partial slots per stat

// ---------------- PROBE: stage+stats skeleton x2 (dead output) ----------------
// Identical to k_convwave minus tap loop and S stores. Two reps with rotated
// column addresses (CSE-proof) -> probe time = 2x skeleton cost.
__global__ __launch_bounds__(256) void k_probe(
    const float* __restrict__ x,
    float* __restrict__ dead)
{
  __shared__ float lds[4][10 * LR];
  const int tid = threadIdx.x;
  const int lane = tid & 63;
  const int w = tid >> 6;
  float* sx = lds[w];

  const int widx = blockIdx.x * 4 + w;
  const int b = widx / 39;
  const int r39 = widx - b * 39;
  const int c = r39 / 13;
  const int band = r39 - c * 13;

  if (lane < 10) sx[lane * LR + 3] = 0.f;
  else if (lane < 20) sx[(lane - 10) * LR + 132] = 0.f;

  const float* xc = x + ((size_t)b * 3 + c) * 16384;
  const int rbase = 10 * band - 1;
  float s = 0.f, q = 0.f;
  #pragma unroll
  for (int rep = 0; rep < 2; rep++) {
    #pragma unroll
    for (int u = 0; u < 5; u++) {
      int v = lane + 64 * u;             // 0..319
      int j = v >> 5;
      int col4 = (((v & 31) + (rep << 4)) & 31) << 2;  // rep1: rotated by 64 floats
      int r = rbase + j;
      float4 a4 = {0.f, 0.f, 0.f, 0.f};
      if (r >= 0 && r < 128) a4 = *(const float4*)(xc + r * 128 + col4);
      *(float4*)(&sx[j * LR + col4 + 4]) = a4;
      s += (a4.x + a4.y) + (a4.z + a4.w);
      q += (a4.x * a4.x + a4.y * a4.y) + (a4.z * a4.z + a4.w * a4.w);
    }
  }
  #pragma unroll
  for (int off = 32; off; off >>= 1) {
    s += __shfl_down(s, off);
    q += __shfl_down(q, off);
  }
  if (lane == 0) {
    int pos = b * 13 + band;
    dead[(size_t)c * NW + pos] = s;
    dead[(size_t)(3 + c) * NW + pos] = q;
  }
}

// ---------------- K1: barrier-free wave-private conv + fused stats ----------------
__global__ __launch_bounds__(256) void k_convwave(
    const float* __restrict__ x,       // [512,3,128,128]
    const float* __restrict__ w1g,     // [3,3,5,5]
    float* __restrict__ S,             // [9][NPOS]
    float* __restrict__ psumA)         // [6][NW]
{
  __shared__ float lds[4][10 * LR];    // 21.76 KB, one slice per wave
  const int tid = threadIdx.x;
  const int lane = tid & 63;
  const int w = tid >> 6;
  float* sx = lds[w];

  const int widx = blockIdx.x * 4 + w; // 0..19967
  const int b = widx / 39;
  const int r39 = widx - b * 39;
  const int c = r39 / 13;
  const int band = r39 - c * 13;
  const int cu = __builtin_amdgcn_readfirstlane(c);

  if (lane < 10) sx[lane * LR + 3] = 0.f;
  else if (lane < 20) sx[(lane - 10) * LR + 132] = 0.f;

  const float* xc = x + ((size_t)b * 3 + c) * 16384;
  const int rbase = 10 * band - 1;
  float s = 0.f, q = 0.f;
  #pragma unroll
  for (int u = 0; u < 5; u++) {
    int v = lane + 64 * u;             // 0..319
    int j = v >> 5;
    int col4 = (v & 31) << 2;
    int r = rbase + j;
    float4 a4 = {0.f, 0.f, 0.f, 0.f};
    if (r >= 0 && r < 128) a4 = *(const float4*)(xc + r * 128 + col4);
    *(float4*)(&sx[j * LR + col4 + 4]) = a4;
    s += (a4.x + a4.y) + (a4.z + a4.w);
    q += (a4.x * a4.x + a4.y * a4.y) + (a4.z * a4.z + a4.w * a4.w);
  }

  const int ol = lane >> 5;
  const int ox = lane & 31;
  if (ox < 26) {
    const float* base = &sx[(5 * ol) * LR + 5 * ox + 3];
    const float* wk = w1g + cu * 25;
    float a0 = 0.f, a1 = 0.f, a2 = 0.f;
    #pragma unroll
    for (int ky = 0; ky < 5; ky++) {
      #pragma unroll
      for (int kx = 0; kx < 5; kx++) {
        float vv = base[ky * LR + kx];
        a0 += wk[ky * 5 + kx] * vv;
        a1 += wk[75 + ky * 5 + kx] * vv;
        a2 += wk[150 + ky * 5 + kx] * vv;
      }
    }
    int oy = 2 * band + ol;
    size_t gp = (size_t)b * 676 + oy * 26 + ox;
    S[(size_t)(c * 3 + 0) * NPOS + gp] = a0;
    S[(size_t)(c * 3 + 1) * NPOS + gp] = a1;
    S[(size_t)(c * 3 + 2) * NPOS + gp] = a2;
  }

  #pragma unroll
  for (int off = 32; off; off >>= 1) {
    s += __shfl_down(s, off);
    q += __shfl_down(q, off);
  }
  if (lane == 0) {
    int pos = b * 13 + band;
    psumA[(size_t)c * NW + pos] = s;
    psumA[(size_t)(3 + c) * NW + pos] = q;
  }
}

// ---------------- K1b: fold NW partials -> 6 stats (one block per stat) ----------------
__global__ __launch_bounds__(1024) void k_reduce(const float* __restrict__ psumA,
                                                 float* __restrict__ stats) {
  const int sidx = blockIdx.x;
  const float* src = psumA + (size_t)sidx * NW;
  float acc = 0.f;
  for (int i = threadIdx.x; i < NW; i += 1024) acc += src[i];
  #pragma unroll
  for (int off = 32; off; off >>= 1) acc += __shfl_down(acc, off);
  __shared__ float r[16];
  if ((threadIdx.x & 63) == 0) r[threadIdx.x >> 6] = acc;
  __syncthreads();
  if (threadIdx.x == 0) {
    float t = 0.f;
    #pragma unroll
    for (int i = 0; i < 16; i++) t += r[i];
    stats[sidx] = t;
  }
}

// ---------------- Kg: gather live fc1 columns -> bf16 B-fragment layout ----------------
__device__ inline float gval(const float* __restrict__ row, int k) {
  if (k >= 2028) return 0.f;
  int c = k / 676;
  int rem = k - c * 676;
  int oy = rem / 26, ox = rem - oy * 26;
  int col = c * 4225 + ((5 * oy) >> 1) * 65 + ((5 * ox) >> 1);
  return row[col];
}

__global__ __launch_bounds__(256) void k_gather(const float* __restrict__ fc1_w,
                                                ushort* __restrict__ WgtB,
                                                ushort* __restrict__ featB) {
  int gid = blockIdx.x * 256 + threadIdx.x;  // 32768 total
  if (gid < 10240)
    featB[(size_t)(gid / 20) * 2048 + 2028 + (gid % 20)] = 0;
  int l = gid & 63;
  int n = ((gid >> 12) << 4) + (l & 15);
  int kbase = (((gid >> 6) & 63) << 5) + ((l >> 4) << 3);
  const float* row = fc1_w + n * 12675;
  uint4 o;
  unsigned int w[4];
  #pragma unroll
  for (int i = 0; i < 4; i++) {
    ushort lo = f2bf(gval(row, kbase + 2 * i));
    ushort hi = f2bf(gval(row, kbase + 2 * i + 1));
    w[i] = (unsigned int)lo | ((unsigned int)hi << 16);
  }
  o.x = w[0]; o.y = w[1]; o.z = w[2]; o.w = w[3];
  ((uint4*)WgtB)[gid] = o;
}

// ---------------- K2: combine S + stats -> feat ----------------
__global__ __launch_bounds__(256) void k_combine(
    const float* __restrict__ S,
    const float* __restrict__ stats,
    const float* __restrict__ gamma, const float* __restrict__ beta,
    const float* __restrict__ w1, const float* __restrict__ b1,
    const float* __restrict__ w2, const float* __restrict__ b2,
    ushort* __restrict__ featB)
{
  __shared__ float s_w1[225];
  __shared__ float s_w2[9];
  __shared__ float s_scale[3], s_shift[3], s_b1[3], s_b2[3];
  __shared__ float s_T[9][9];
  const int tid = threadIdx.x;
  if (tid < 225) s_w1[tid] = w1[tid];
  if (tid < 9) s_w2[tid] = w2[tid * 25];
  if (tid < 3) {
    const float N = 512.f * 128.f * 128.f;
    float mean = stats[tid] / N;
    float var = stats[3 + tid] / N - mean * mean;
    float sc = gamma[tid] * rsqrtf(var + BN_EPS);
    s_scale[tid] = sc;
    s_shift[tid] = beta[tid] - mean * sc;
    s_b1[tid] = b1[tid];
    s_b2[tid] = b2[tid];
  }
  __syncthreads();
  if (tid < 81) {
    int cls = tid / 9, oc = tid - (tid / 9) * 9;
    int rcl = cls / 3, ccl = cls - rcl * 3;
    int o = oc / 3, c = oc - o * 3;
    int ky0 = (rcl == 0) ? 1 : 0, ky1 = (rcl == 2) ? 3 : 4;
    int kx0 = (ccl == 0) ? 1 : 0, kx1 = (ccl == 2) ? 3 : 4;
    float t = 0.f;
    for (int ky = ky0; ky <= ky1; ky++)
      for (int kx = kx0; kx <= kx1; kx++)
        t += s_w1[o * 75 + c * 25 + ky * 5 + kx];
    s_T[cls][oc] = t;
  }
  __syncthreads();

  int gpos = blockIdx.x * 256 + tid;
  int b = gpos / 676;
  int pos = gpos - b * 676;
  int oy = pos / 26, ox = pos - oy * 26;
  int rcl = (oy == 0) ? 0 : ((oy == 25) ? 2 : 1);
  int ccl = (ox == 0) ? 0 : ((ox == 25) ? 2 : 1);
  int cls = rcl * 3 + ccl;

  float h[3];
  #pragma unroll
  for (int o = 0; o < 3; o++) {
    float a = s_b1[o];
    #pragma unroll
    for (int c = 0; c < 3; c++) {
      a += s_scale[c] * S[(size_t)(c * 3 + o) * NPOS + gpos];
      a += s_shift[c] * s_T[cls][o * 3 + c];
    }
    h[o] = fmaxf(a, 0.f);
  }
  ushort* fb = featB + (size_t)b * 2048;
  #pragma unroll
  for (int o = 0; o < 3; o++) {
    float v = s_b2[o] + s_w2[3 * o] * h[0] + s_w2[3 * o + 1] * h[1] + s_w2[3 * o + 2] * h[2];
    fb[o * 676 + pos] = f2bf(fmaxf(v, 0.f));
  }
}

// ---------------- K3: fc1 via MFMA + relu + fc2 + log_softmax ----------------
__global__ __launch_bounds__(512) void k_fc(
    const ushort* __restrict__ featB,
    const ushort* __restrict__ WgtB,
    const float* __restrict__ fc1_b,
    const float* __restrict__ fc2_w, const float* __restrict__ fc2_b,
    float* __restrict__ out)
{
  __shared__ float s_f[16][132];
  __shared__ float s_lg[16][10];
  const int tid = threadIdx.x;
  const int lane = tid & 63;
  const int t = tid >> 6;
  const int m0 = blockIdx.x * 16;

  const ushort* aptr = featB + (size_t)(m0 + (lane & 15)) * 2048 + ((lane >> 4) << 3);
  const ushort* bptr = WgtB + ((size_t)t * 4096 + lane) * 8;

  f32x4 acc = {0.f, 0.f, 0.f, 0.f};
  #pragma unroll 4
  for (int kk = 0; kk < 64; kk++) {
    short8 a = *(const short8*)(aptr + kk * 32);
    short8 bfr = *(const short8*)(bptr + kk * 512);
    acc = __builtin_amdgcn_mfma_f32_16x16x32_bf16(a, bfr, acc, 0, 0, 0);
  }
  {
    int n = t * 16 + (lane & 15);
    float bias = fc1_b[n];
    int mb = (lane >> 4) << 2;
    #pragma unroll
    for (int r = 0; r < 4; r++)
      s_f[mb + r][n] = fmaxf(acc[r] + bias, 0.f);
  }
  __syncthreads();

  if (tid < 160) {
    int m = tid & 15, q = tid >> 4;
    const float* wr = fc2_w + q * 128;
    float a2 = fc2_b[q];
    #pragma unroll 8
    for (int n = 0; n < 128; n++) a2 += wr[n] * s_f[m][n];
    s_lg[m][q] = a2;
  }
  __syncthreads();

  if (tid < 16) {
    float mx = s_lg[tid][0];
    #pragma unroll
    for (int q = 1; q < 10; q++) mx = fmaxf(mx, s_lg[tid][q]);
    float se = 0.f;
    #pragma unroll
    for (int q = 0; q < 10; q++) se += expf(s_lg[tid][q] - mx);
    float lse = mx + logf(se);
    float* op = out + (size_t)(m0 + tid) * 10;
    #pragma unroll
    for (int q = 0; q < 10; q++) op[q] = s_lg[tid][q] - lse;
  }
}

extern "C" void kernel_launch(void* const* d_in, const int* in_sizes, int n_in,
                              void* d_out, int out_size, void* d_ws, size_t ws_size,
                              hipStream_t stream) {
  const float* x      = (const float*)d_in[0];
  const float* gamma  = (const float*)d_in[1];
  const float* beta   = (const float*)d_in[2];
  const float* w1     = (const float*)d_in[3];
  const float* b1     = (const float*)d_in[4];
  const float* w2     = (const float*)d_in[5];
  const float* b2     = (const float*)d_in[6];
  const float* fc1_w  = (const float*)d_in[7];
  const float* fc1_b  = (const float*)d_in[8];
  const float* fc2_w  = (const float*)d_in[9];
  const float* fc2_b  = (const float*)d_in[10];
  float* out = (float*)d_out;
  float* wsf = (float*)d_ws;

  float* stats  = wsf;                      // [0..5]
  float* psumA  = wsf + 64;                 // [6][6656]
  float* deadp  = wsf + 45056;              // probe dead region
  ushort* WgtB  = (ushort*)(wsf + 131072);  // 512 KB bf16
  ushort* featB = (ushort*)(wsf + 262144);  // 2 MB bf16
  float* S      = wsf + 786432;             // [9][NPOS] = 12.5 MB

  k_probe<<<4992, 256, 0, stream>>>(x, deadp);
  k_convwave<<<4992, 256, 0, stream>>>(x, w1, S, psumA);
  k_gather<<<128, 256, 0, stream>>>(fc1_w, WgtB, featB);
  k_reduce<<<6, 1024, 0, stream>>>(psumA, stats);
  k_combine<<<1352, 256, 0, stream>>>(S, stats, gamma, beta, w1, b1, w2, b2, featB);
  k_fc<<<32, 512, 0, stream>>>(featB, WgtB, fc1_b, fc2_w, fc2_b, out);
}

// Round 13
// 58.846 us; speedup vs baseline: 1.2956x; 1.2956x over previous
//
#include <hip/hip_runtime.h>

#define BN_EPS 1e-5f

typedef short short8 __attribute__((ext_vector_type(8)));
typedef float f32x4 __attribute__((ext_vector_type(4)));
typedef unsigned short ushort;

__device__ inline ushort f2bf(float f) {
  unsigned int u = __float_as_uint(f);
  u += 0x7FFFu + ((u >> 16) & 1u);
  return (ushort)(u >> 16);
}

// ws float-word layout:
//   [0..5]           stats (3 sums, 3 sumsqs)
//   [64..39999]      psumA [6][6656]
//   [131072..262143] WgtB  bf16 (512 KB)
//   [262144..524287] featB bf16 [512][2048] (2 MB)
//   [786432..]       S     [9][346112] fp32 (12.5 MB)

#define NPOS 346112  // 512*676
#define LR 136       // per-wave LDS row stride (floats)
#define NW 6656      // 512*13 partial slots per stat
#define WPG 4992     // waves in grid (1248 blocks x 4)

// ---------------- K1: wave-private conv, 4 units/wave, register prefetch ----------------
// Unit = (b, c, band of 2 output rows); unit id = it*WPG + global_wave.
// Per unit: stage 10 rows into the wave's OWN LDS slice (no barriers), fused stats,
// 25-tap conv for 52 positions. Next unit's global loads issue before current taps.
__global__ __launch_bounds__(256) void k_convwave(
    const float* __restrict__ x,       // [512,3,128,128]
    const float* __restrict__ w1g,     // [3,3,5,5]
    float* __restrict__ S,             // [9][NPOS]
    float* __restrict__ psumA)         // [6][NW]
{
  __shared__ float lds[4][10 * LR];    // 21.76 KB, one slice per wave
  const int tid = threadIdx.x;
  const int lane = tid & 63;
  const int w = tid >> 6;
  float* sx = lds[w];

  // zero column pads once (slice reused across units; stages never touch cols 3/132)
  if (lane < 10) sx[lane * LR + 3] = 0.f;
  else if (lane < 20) sx[(lane - 10) * LR + 132] = 0.f;

  const int wave0 = blockIdx.x * 4 + w;   // 0..4991

  // ---- prefetch unit 0 ----
  int widx = wave0;
  int b = widx / 39;
  int r39 = widx - b * 39;
  int c = r39 / 13;
  int band = r39 - c * 13;
  float4 pf0, pf1, pf2, pf3, pf4;
  {
    const float* xc = x + ((size_t)b * 3 + c) * 16384;
    int rbase = 10 * band - 1;
    const float4 z = {0.f, 0.f, 0.f, 0.f};
    #pragma unroll
    for (int u5 = 0; u5 < 5; u5++) {
      int v = lane + 64 * u5;
      int j = v >> 5, col4 = (v & 31) << 2;
      int r = rbase + j;
      float4 a4 = (r >= 0 && r < 128) ? *(const float4*)(xc + r * 128 + col4) : z;
      if (u5 == 0) pf0 = a4; else if (u5 == 1) pf1 = a4; else if (u5 == 2) pf2 = a4;
      else if (u5 == 3) pf3 = a4; else pf4 = a4;
    }
  }

  #pragma unroll
  for (int it = 0; it < 4; it++) {
    // current unit coords + data
    const int bC = b, cC = c, bandC = band;
    float4 c0 = pf0, c1 = pf1, c2 = pf2, c3 = pf3, c4 = pf4;

    // ---- issue next unit's loads (hide HBM latency under this unit's taps) ----
    if (it < 3) {
      widx = wave0 + (it + 1) * WPG;
      b = widx / 39;
      r39 = widx - b * 39;
      c = r39 / 13;
      band = r39 - c * 13;
      const float* xc = x + ((size_t)b * 3 + c) * 16384;
      int rbase = 10 * band - 1;
      const float4 z = {0.f, 0.f, 0.f, 0.f};
      #pragma unroll
      for (int u5 = 0; u5 < 5; u5++) {
        int v = lane + 64 * u5;
        int j = v >> 5, col4 = (v & 31) << 2;
        int r = rbase + j;
        float4 a4 = (r >= 0 && r < 128) ? *(const float4*)(xc + r * 128 + col4) : z;
        if (u5 == 0) pf0 = a4; else if (u5 == 1) pf1 = a4; else if (u5 == 2) pf2 = a4;
        else if (u5 == 3) pf3 = a4; else pf4 = a4;
      }
    }

    // ---- stage current unit into LDS + fused stats ----
    float s = 0.f, q = 0.f;
    #pragma unroll
    for (int u5 = 0; u5 < 5; u5++) {
      float4 a4 = (u5 == 0) ? c0 : (u5 == 1) ? c1 : (u5 == 2) ? c2 : (u5 == 3) ? c3 : c4;
      int v = lane + 64 * u5;
      int j = v >> 5, col4 = (v & 31) << 2;
      *(float4*)(&sx[j * LR + col4 + 4]) = a4;
      s += (a4.x + a4.y) + (a4.z + a4.w);
      q += (a4.x * a4.x + a4.y * a4.y) + (a4.z * a4.z + a4.w * a4.w);
    }

    // ---- 25-tap conv for 52 positions ----
    const int cu = __builtin_amdgcn_readfirstlane(cC);
    const int ol = lane >> 5;
    const int ox = lane & 31;
    if (ox < 26) {
      const float* base = &sx[(5 * ol) * LR + 5 * ox + 3];
      const float* wk = w1g + cu * 25;
      float a0 = 0.f, a1 = 0.f, a2 = 0.f;
      #pragma unroll
      for (int ky = 0; ky < 5; ky++) {
        #pragma unroll
        for (int kx = 0; kx < 5; kx++) {
          float vv = base[ky * LR + kx];
          a0 += wk[ky * 5 + kx] * vv;
          a1 += wk[75 + ky * 5 + kx] * vv;
          a2 += wk[150 + ky * 5 + kx] * vv;
        }
      }
      int oy = 2 * bandC + ol;
      size_t gp = (size_t)bC * 676 + oy * 26 + ox;
      S[(size_t)(cC * 3 + 0) * NPOS + gp] = a0;
      S[(size_t)(cC * 3 + 1) * NPOS + gp] = a1;
      S[(size_t)(cC * 3 + 2) * NPOS + gp] = a2;
    }

    // ---- wave-local stats reduce -> psumA ----
    #pragma unroll
    for (int off = 32; off; off >>= 1) {
      s += __shfl_down(s, off);
      q += __shfl_down(q, off);
    }
    if (lane == 0) {
      int pos = bC * 13 + bandC;
      psumA[(size_t)cC * NW + pos] = s;
      psumA[(size_t)(3 + cC) * NW + pos] = q;
    }
  }
}

// ---------------- K1b: fold NW partials -> 6 stats (one block per stat) ----------------
__global__ __launch_bounds__(1024) void k_reduce(const float* __restrict__ psumA,
                                                 float* __restrict__ stats) {
  const int sidx = blockIdx.x;
  const float* src = psumA + (size_t)sidx * NW;
  float acc = 0.f;
  for (int i = threadIdx.x; i < NW; i += 1024) acc += src[i];
  #pragma unroll
  for (int off = 32; off; off >>= 1) acc += __shfl_down(acc, off);
  __shared__ float r[16];
  if ((threadIdx.x & 63) == 0) r[threadIdx.x >> 6] = acc;
  __syncthreads();
  if (threadIdx.x == 0) {
    float t = 0.f;
    #pragma unroll
    for (int i = 0; i < 16; i++) t += r[i];
    stats[sidx] = t;
  }
}

// ---------------- Kg: gather live fc1 columns -> bf16 B-fragment layout ----------------
__device__ inline float gval(const float* __restrict__ row, int k) {
  if (k >= 2028) return 0.f;
  int c = k / 676;
  int rem = k - c * 676;
  int oy = rem / 26, ox = rem - oy * 26;
  int col = c * 4225 + ((5 * oy) >> 1) * 65 + ((5 * ox) >> 1);
  return row[col];
}

__global__ __launch_bounds__(256) void k_gather(const float* __restrict__ fc1_w,
                                                ushort* __restrict__ WgtB,
                                                ushort* __restrict__ featB) {
  int gid = blockIdx.x * 256 + threadIdx.x;  // 32768 total
  if (gid < 10240)
    featB[(size_t)(gid / 20) * 2048 + 2028 + (gid % 20)] = 0;
  int l = gid & 63;
  int n = ((gid >> 12) << 4) + (l & 15);
  int kbase = (((gid >> 6) & 63) << 5) + ((l >> 4) << 3);
  const float* row = fc1_w + n * 12675;
  uint4 o;
  unsigned int w[4];
  #pragma unroll
  for (int i = 0; i < 4; i++) {
    ushort lo = f2bf(gval(row, kbase + 2 * i));
    ushort hi = f2bf(gval(row, kbase + 2 * i + 1));
    w[i] = (unsigned int)lo | ((unsigned int)hi << 16);
  }
  o.x = w[0]; o.y = w[1]; o.z = w[2]; o.w = w[3];
  ((uint4*)WgtB)[gid] = o;
}

// ---------------- K2: combine S + stats -> feat ----------------
__global__ __launch_bounds__(256) void k_combine(
    const float* __restrict__ S,
    const float* __restrict__ stats,
    const float* __restrict__ gamma, const float* __restrict__ beta,
    const float* __restrict__ w1, const float* __restrict__ b1,
    const float* __restrict__ w2, const float* __restrict__ b2,
    ushort* __restrict__ featB)
{
  __shared__ float s_w1[225];
  __shared__ float s_w2[9];
  __shared__ float s_scale[3], s_shift[3], s_b1[3], s_b2[3];
  __shared__ float s_T[9][9];
  const int tid = threadIdx.x;
  if (tid < 225) s_w1[tid] = w1[tid];
  if (tid < 9) s_w2[tid] = w2[tid * 25];
  if (tid < 3) {
    const float N = 512.f * 128.f * 128.f;
    float mean = stats[tid] / N;
    float var = stats[3 + tid] / N - mean * mean;
    float sc = gamma[tid] * rsqrtf(var + BN_EPS);
    s_scale[tid] = sc;
    s_shift[tid] = beta[tid] - mean * sc;
    s_b1[tid] = b1[tid];
    s_b2[tid] = b2[tid];
  }
  __syncthreads();
  if (tid < 81) {
    int cls = tid / 9, oc = tid - (tid / 9) * 9;
    int rcl = cls / 3, ccl = cls - rcl * 3;
    int o = oc / 3, c = oc - o * 3;
    int ky0 = (rcl == 0) ? 1 : 0, ky1 = (rcl == 2) ? 3 : 4;
    int kx0 = (ccl == 0) ? 1 : 0, kx1 = (ccl == 2) ? 3 : 4;
    float t = 0.f;
    for (int ky = ky0; ky <= ky1; ky++)
      for (int kx = kx0; kx <= kx1; kx++)
        t += s_w1[o * 75 + c * 25 + ky * 5 + kx];
    s_T[cls][oc] = t;
  }
  __syncthreads();

  int gpos = blockIdx.x * 256 + tid;
  int b = gpos / 676;
  int pos = gpos - b * 676;
  int oy = pos / 26, ox = pos - oy * 26;
  int rcl = (oy == 0) ? 0 : ((oy == 25) ? 2 : 1);
  int ccl = (ox == 0) ? 0 : ((ox == 25) ? 2 : 1);
  int cls = rcl * 3 + ccl;

  float h[3];
  #pragma unroll
  for (int o = 0; o < 3; o++) {
    float a = s_b1[o];
    #pragma unroll
    for (int c = 0; c < 3; c++) {
      a += s_scale[c] * S[(size_t)(c * 3 + o) * NPOS + gpos];
      a += s_shift[c] * s_T[cls][o * 3 + c];
    }
    h[o] = fmaxf(a, 0.f);
  }
  ushort* fb = featB + (size_t)b * 2048;
  #pragma unroll
  for (int o = 0; o < 3; o++) {
    float v = s_b2[o] + s_w2[3 * o] * h[0] + s_w2[3 * o + 1] * h[1] + s_w2[3 * o + 2] * h[2];
    fb[o * 676 + pos] = f2bf(fmaxf(v, 0.f));
  }
}

// ---------------- K3: fc1 via MFMA + relu + fc2 + log_softmax ----------------
__global__ __launch_bounds__(512) void k_fc(
    const ushort* __restrict__ featB,
    const ushort* __restrict__ WgtB,
    const float* __restrict__ fc1_b,
    const float* __restrict__ fc2_w, const float* __restrict__ fc2_b,
    float* __restrict__ out)
{
  __shared__ float s_f[16][132];
  __shared__ float s_lg[16][10];
  const int tid = threadIdx.x;
  const int lane = tid & 63;
  const int t = tid >> 6;
  const int m0 = blockIdx.x * 16;

  const ushort* aptr = featB + (size_t)(m0 + (lane & 15)) * 2048 + ((lane >> 4) << 3);
  const ushort* bptr = WgtB + ((size_t)t * 4096 + lane) * 8;

  f32x4 acc = {0.f, 0.f, 0.f, 0.f};
  #pragma unroll 4
  for (int kk = 0; kk < 64; kk++) {
    short8 a = *(const short8*)(aptr + kk * 32);
    short8 bfr = *(const short8*)(bptr + kk * 512);
    acc = __builtin_amdgcn_mfma_f32_16x16x32_bf16(a, bfr, acc, 0, 0, 0);
  }
  {
    int n = t * 16 + (lane & 15);
    float bias = fc1_b[n];
    int mb = (lane >> 4) << 2;
    #pragma unroll
    for (int r = 0; r < 4; r++)
      s_f[mb + r][n] = fmaxf(acc[r] + bias, 0.f);
  }
  __syncthreads();

  if (tid < 160) {
    int m = tid & 15, q = tid >> 4;
    const float* wr = fc2_w + q * 128;
    float a2 = fc2_b[q];
    #pragma unroll 8
    for (int n = 0; n < 128; n++) a2 += wr[n] * s_f[m][n];
    s_lg[m][q] = a2;
  }
  __syncthreads();

  if (tid < 16) {
    float mx = s_lg[tid][0];
    #pragma unroll
    for (int q = 1; q < 10; q++) mx = fmaxf(mx, s_lg[tid][q]);
    float se = 0.f;
    #pragma unroll
    for (int q = 0; q < 10; q++) se += expf(s_lg[tid][q] - mx);
    float lse = mx + logf(se);
    float* op = out + (size_t)(m0 + tid) * 10;
    #pragma unroll
    for (int q = 0; q < 10; q++) op[q] = s_lg[tid][q] - lse;
  }
}

extern "C" void kernel_launch(void* const* d_in, const int* in_sizes, int n_in,
                              void* d_out, int out_size, void* d_ws, size_t ws_size,
                              hipStream_t stream) {
  const float* x      = (const float*)d_in[0];
  const float* gamma  = (const float*)d_in[1];
  const float* beta   = (const float*)d_in[2];
  const float* w1     = (const float*)d_in[3];
  const float* b1     = (const float*)d_in[4];
  const float* w2     = (const float*)d_in[5];
  const float* b2     = (const float*)d_in[6];
  const float* fc1_w  = (const float*)d_in[7];
  const float* fc1_b  = (const float*)d_in[8];
  const float* fc2_w  = (const float*)d_in[9];
  const float* fc2_b  = (const float*)d_in[10];
  float* out = (float*)d_out;
  float* wsf = (float*)d_ws;

  float* stats  = wsf;                      // [0..5]
  float* psumA  = wsf + 64;                 // [6][6656]
  ushort* WgtB  = (ushort*)(wsf + 131072);  // 512 KB bf16
  ushort* featB = (ushort*)(wsf + 262144);  // 2 MB bf16
  float* S      = wsf + 786432;             // [9][NPOS] = 12.5 MB

  k_convwave<<<1248, 256, 0, stream>>>(x, w1, S, psumA);
  k_gather<<<128, 256, 0, stream>>>(fc1_w, WgtB, featB);
  k_reduce<<<6, 1024, 0, stream>>>(psumA, stats);
  k_combine<<<1352, 256, 0, stream>>>(S, stats, gamma, beta, w1, b1, w2, b2, featB);
  k_fc<<<32, 512, 0, stream>>>(featB, WgtB, fc1_b, fc2_w, fc2_b, out);
}

// Round 14
// 57.961 us; speedup vs baseline: 1.3154x; 1.0153x over previous
//
#include <hip/hip_runtime.h>

#define BN_EPS 1e-5f

typedef short short8 __attribute__((ext_vector_type(8)));
typedef float f32x4 __attribute__((ext_vector_type(4)));
typedef unsigned short ushort;

__device__ inline ushort f2bf(float f) {
  unsigned int u = __float_as_uint(f);
  u += 0x7FFFu + ((u >> 16) & 1u);
  return (ushort)(u >> 16);
}

// ws float-word layout:
//   [0..5]           stats (3 sums, 3 sumsqs)
//   [64..39999]      psumA [6][6656]
//   [131072..262143] WgtB  bf16 (512 KB)
//   [262144..524287] featB bf16 [512][2048] (2 MB)
//   [786432..]       S     [9][346112] fp32 (12.5 MB)

#define NPOS 346112  // 512*676
#define NW 6656      // 512*13 partial slots per stat

// ---------------- K1: no-LDS direct conv + fused stats ----------------
// Wave = (b, c, band of 2 output rows). Windows are DISJOINT (k=5,s=5, pad 1):
// lane (ol, ox) owns input rows 10*band+5*ol-1..+3, cols 5*ox-1..+3 exclusively.
// 25 predicated global loads per lane, no LDS anywhere, stats fused (each real
// x element is loaded by exactly one lane-tap).
__global__ __launch_bounds__(256) void k_convdirect(
    const float* __restrict__ x,       // [512,3,128,128]
    const float* __restrict__ w1g,     // [3,3,5,5]
    float* __restrict__ S,             // [9][NPOS]
    float* __restrict__ psumA)         // [6][NW]
{
  const int tid = threadIdx.x;
  const int lane = tid & 63;
  const int w = tid >> 6;
  const int widx = blockIdx.x * 4 + w; // 0..19967
  const int b = widx / 39;
  const int r39 = widx - b * 39;
  const int c = r39 / 13;
  const int band = r39 - c * 13;
  const int cu = __builtin_amdgcn_readfirstlane(c);

  const int ol = lane >> 5;            // output-row half
  const int ox = lane & 31;            // output col (active < 26)
  const bool active = ox < 26;
  const float* xc = x + ((size_t)b * 3 + c) * 16384;
  const int r0 = 10 * band + 5 * ol - 1;
  const int cbase = 5 * ox - 1;

  const float* wk = w1g + cu * 25;     // SGPR base -> scalar weight loads
  float a0 = 0.f, a1 = 0.f, a2 = 0.f, s = 0.f, q = 0.f;
  #pragma unroll
  for (int ky = 0; ky < 5; ky++) {
    int r = r0 + ky;
    bool rok = (r >= 0) && (r < 128);
    const float* xr = xc + r * 128;
    #pragma unroll
    for (int kx = 0; kx < 5; kx++) {
      int col = cbase + kx;
      bool ok = active && rok && (col >= 0) && (col < 128);
      float v = ok ? xr[col] : 0.f;    // predicated load, lane-private address
      s += v;
      q += v * v;
      a0 += wk[ky * 5 + kx] * v;
      a1 += wk[75 + ky * 5 + kx] * v;
      a2 += wk[150 + ky * 5 + kx] * v;
    }
  }

  if (active) {
    int oy = 2 * band + ol;
    size_t gp = (size_t)b * 676 + oy * 26 + ox;
    S[(size_t)(c * 3 + 0) * NPOS + gp] = a0;
    S[(size_t)(c * 3 + 1) * NPOS + gp] = a1;
    S[(size_t)(c * 3 + 2) * NPOS + gp] = a2;
  }

  // wave-local stats reduce -> psumA (every real element counted exactly once)
  #pragma unroll
  for (int off = 32; off; off >>= 1) {
    s += __shfl_down(s, off);
    q += __shfl_down(q, off);
  }
  if (lane == 0) {
    int pos = b * 13 + band;
    psumA[(size_t)c * NW + pos] = s;
    psumA[(size_t)(3 + c) * NW + pos] = q;
  }
}

// ---------------- K1b: fold NW partials -> 6 stats (one block per stat) ----------------
__global__ __launch_bounds__(1024) void k_reduce(const float* __restrict__ psumA,
                                                 float* __restrict__ stats) {
  const int sidx = blockIdx.x;
  const float* src = psumA + (size_t)sidx * NW;
  float acc = 0.f;
  for (int i = threadIdx.x; i < NW; i += 1024) acc += src[i];
  #pragma unroll
  for (int off = 32; off; off >>= 1) acc += __shfl_down(acc, off);
  __shared__ float r[16];
  if ((threadIdx.x & 63) == 0) r[threadIdx.x >> 6] = acc;
  __syncthreads();
  if (threadIdx.x == 0) {
    float t = 0.f;
    #pragma unroll
    for (int i = 0; i < 16; i++) t += r[i];
    stats[sidx] = t;
  }
}

// ---------------- Kg: gather live fc1 columns -> bf16 B-fragment layout ----------------
__device__ inline float gval(const float* __restrict__ row, int k) {
  if (k >= 2028) return 0.f;
  int c = k / 676;
  int rem = k - c * 676;
  int oy = rem / 26, ox = rem - oy * 26;
  int col = c * 4225 + ((5 * oy) >> 1) * 65 + ((5 * ox) >> 1);
  return row[col];
}

__global__ __launch_bounds__(256) void k_gather(const float* __restrict__ fc1_w,
                                                ushort* __restrict__ WgtB,
                                                ushort* __restrict__ featB) {
  int gid = blockIdx.x * 256 + threadIdx.x;  // 32768 total
  if (gid < 10240)
    featB[(size_t)(gid / 20) * 2048 + 2028 + (gid % 20)] = 0;
  int l = gid & 63;
  int n = ((gid >> 12) << 4) + (l & 15);
  int kbase = (((gid >> 6) & 63) << 5) + ((l >> 4) << 3);
  const float* row = fc1_w + n * 12675;
  uint4 o;
  unsigned int w[4];
  #pragma unroll
  for (int i = 0; i < 4; i++) {
    ushort lo = f2bf(gval(row, kbase + 2 * i));
    ushort hi = f2bf(gval(row, kbase + 2 * i + 1));
    w[i] = (unsigned int)lo | ((unsigned int)hi << 16);
  }
  o.x = w[0]; o.y = w[1]; o.z = w[2]; o.w = w[3];
  ((uint4*)WgtB)[gid] = o;
}

// ---------------- K2: combine S + stats -> feat ----------------
__global__ __launch_bounds__(256) void k_combine(
    const float* __restrict__ S,
    const float* __restrict__ stats,
    const float* __restrict__ gamma, const float* __restrict__ beta,
    const float* __restrict__ w1, const float* __restrict__ b1,
    const float* __restrict__ w2, const float* __restrict__ b2,
    ushort* __restrict__ featB)
{
  __shared__ float s_w1[225];
  __shared__ float s_w2[9];
  __shared__ float s_scale[3], s_shift[3], s_b1[3], s_b2[3];
  __shared__ float s_T[9][9];
  const int tid = threadIdx.x;
  if (tid < 225) s_w1[tid] = w1[tid];
  if (tid < 9) s_w2[tid] = w2[tid * 25];
  if (tid < 3) {
    const float N = 512.f * 128.f * 128.f;
    float mean = stats[tid] / N;
    float var = stats[3 + tid] / N - mean * mean;
    float sc = gamma[tid] * rsqrtf(var + BN_EPS);
    s_scale[tid] = sc;
    s_shift[tid] = beta[tid] - mean * sc;
    s_b1[tid] = b1[tid];
    s_b2[tid] = b2[tid];
  }
  __syncthreads();
  if (tid < 81) {
    int cls = tid / 9, oc = tid - (tid / 9) * 9;
    int rcl = cls / 3, ccl = cls - rcl * 3;
    int o = oc / 3, c = oc - o * 3;
    int ky0 = (rcl == 0) ? 1 : 0, ky1 = (rcl == 2) ? 3 : 4;
    int kx0 = (ccl == 0) ? 1 : 0, kx1 = (ccl == 2) ? 3 : 4;
    float t = 0.f;
    for (int ky = ky0; ky <= ky1; ky++)
      for (int kx = kx0; kx <= kx1; kx++)
        t += s_w1[o * 75 + c * 25 + ky * 5 + kx];
    s_T[cls][oc] = t;
  }
  __syncthreads();

  int gpos = blockIdx.x * 256 + tid;
  int b = gpos / 676;
  int pos = gpos - b * 676;
  int oy = pos / 26, ox = pos - oy * 26;
  int rcl = (oy == 0) ? 0 : ((oy == 25) ? 2 : 1);
  int ccl = (ox == 0) ? 0 : ((ox == 25) ? 2 : 1);
  int cls = rcl * 3 + ccl;

  float h[3];
  #pragma unroll
  for (int o = 0; o < 3; o++) {
    float a = s_b1[o];
    #pragma unroll
    for (int c = 0; c < 3; c++) {
      a += s_scale[c] * S[(size_t)(c * 3 + o) * NPOS + gpos];
      a += s_shift[c] * s_T[cls][o * 3 + c];
    }
    h[o] = fmaxf(a, 0.f);
  }
  ushort* fb = featB + (size_t)b * 2048;
  #pragma unroll
  for (int o = 0; o < 3; o++) {
    float v = s_b2[o] + s_w2[3 * o] * h[0] + s_w2[3 * o + 1] * h[1] + s_w2[3 * o + 2] * h[2];
    fb[o * 676 + pos] = f2bf(fmaxf(v, 0.f));
  }
}

// ---------------- K3: fc1 via MFMA + relu + fc2 + log_softmax ----------------
__global__ __launch_bounds__(512) void k_fc(
    const ushort* __restrict__ featB,
    const ushort* __restrict__ WgtB,
    const float* __restrict__ fc1_b,
    const float* __restrict__ fc2_w, const float* __restrict__ fc2_b,
    float* __restrict__ out)
{
  __shared__ float s_f[16][132];
  __shared__ float s_lg[16][10];
  const int tid = threadIdx.x;
  const int lane = tid & 63;
  const int t = tid >> 6;
  const int m0 = blockIdx.x * 16;

  const ushort* aptr = featB + (size_t)(m0 + (lane & 15)) * 2048 + ((lane >> 4) << 3);
  const ushort* bptr = WgtB + ((size_t)t * 4096 + lane) * 8;

  f32x4 acc = {0.f, 0.f, 0.f, 0.f};
  #pragma unroll 4
  for (int kk = 0; kk < 64; kk++) {
    short8 a = *(const short8*)(aptr + kk * 32);
    short8 bfr = *(const short8*)(bptr + kk * 512);
    acc = __builtin_amdgcn_mfma_f32_16x16x32_bf16(a, bfr, acc, 0, 0, 0);
  }
  {
    int n = t * 16 + (lane & 15);
    float bias = fc1_b[n];
    int mb = (lane >> 4) << 2;
    #pragma unroll
    for (int r = 0; r < 4; r++)
      s_f[mb + r][n] = fmaxf(acc[r] + bias, 0.f);
  }
  __syncthreads();

  if (tid < 160) {
    int m = tid & 15, q = tid >> 4;
    const float* wr = fc2_w + q * 128;
    float a2 = fc2_b[q];
    #pragma unroll 8
    for (int n = 0; n < 128; n++) a2 += wr[n] * s_f[m][n];
    s_lg[m][q] = a2;
  }
  __syncthreads();

  if (tid < 16) {
    float mx = s_lg[tid][0];
    #pragma unroll
    for (int q = 1; q < 10; q++) mx = fmaxf(mx, s_lg[tid][q]);
    float se = 0.f;
    #pragma unroll
    for (int q = 0; q < 10; q++) se += expf(s_lg[tid][q] - mx);
    float lse = mx + logf(se);
    float* op = out + (size_t)(m0 + tid) * 10;
    #pragma unroll
    for (int q = 0; q < 10; q++) op[q] = s_lg[tid][q] - lse;
  }
}

extern "C" void kernel_launch(void* const* d_in, const int* in_sizes, int n_in,
                              void* d_out, int out_size, void* d_ws, size_t ws_size,
                              hipStream_t stream) {
  const float* x      = (const float*)d_in[0];
  const float* gamma  = (const float*)d_in[1];
  const float* beta   = (const float*)d_in[2];
  const float* w1     = (const float*)d_in[3];
  const float* b1     = (const float*)d_in[4];
  const float* w2     = (const float*)d_in[5];
  const float* b2     = (const float*)d_in[6];
  const float* fc1_w  = (const float*)d_in[7];
  const float* fc1_b  = (const float*)d_in[8];
  const float* fc2_w  = (const float*)d_in[9];
  const float* fc2_b  = (const float*)d_in[10];
  float* out = (float*)d_out;
  float* wsf = (float*)d_ws;

  float* stats  = wsf;                      // [0..5]
  float* psumA  = wsf + 64;                 // [6][6656]
  ushort* WgtB  = (ushort*)(wsf + 131072);  // 512 KB bf16
  ushort* featB = (ushort*)(wsf + 262144);  // 2 MB bf16
  float* S      = wsf + 786432;             // [9][NPOS] = 12.5 MB

  k_convdirect<<<4992, 256, 0, stream>>>(x, w1, S, psumA);
  k_gather<<<128, 256, 0, stream>>>(fc1_w, WgtB, featB);
  k_reduce<<<6, 1024, 0, stream>>>(psumA, stats);
  k_combine<<<1352, 256, 0, stream>>>(S, stats, gamma, beta, w1, b1, w2, b2, featB);
  k_fc<<<32, 512, 0, stream>>>(featB, WgtB, fc1_b, fc2_w, fc2_b, out);
}